// Round 22
// baseline (131.805 us; speedup 1.0000x reference)
//
#include <hip/hip_runtime.h>

#define BATCH 512
#define TLEN  2048
#define NST   24
#define ESTR  28          // floats per row of the phase-A transpose buffer
#define EWRD  20          // u32 words per packed E row: 12 bf16-pairs + lognorm + 7 pad (80B, 5 quads, coprime with 8)
#define NCTX  100         // ctx = (c2*5 + c1)*4 + c0  (c2,c1 in 0..4, c0 in 0..3)
#define CBT   64          // coarse chunks (phase A matrices, phase B scan length)
#define SLC   4           // rows staged per phase-C slice
#define SEGF  100         // padded floats per staged segment (96 data + 4 pad)

typedef float v2f __attribute__((ext_vector_type(2)));

__device__ __forceinline__ unsigned short f2bf(float x) {
  unsigned u = __float_as_uint(x);
  u += 0x7FFFu + ((u >> 16) & 1u);
  return (unsigned short)(u >> 16);
}

__device__ __forceinline__ float sload(const float* p) {
  return __uint_as_float(__builtin_amdgcn_readfirstlane(__float_as_uint(*p)));
}

// R[dst] = sum over edges (src->dst) of A[edge]*f[src].
// STRUCTURE-OPT: single-edge rows have softmax == exactly 1.0 -> identity edges.
__device__ __forceinline__ void at_update(const float* __restrict__ A,
                                          const float* __restrict__ f,
                                          float* __restrict__ R) {
  R[0]  = A[0]*f[0];
  R[1]  = A[1]*f[0];
  R[2]  = f[1];
  R[3]  = f[2];
  R[4]  = A[4]*f[3]  + A[24]*f[16];
  R[5]  = f[4];
  R[6]  = f[5];
  R[7]  = A[6]*f[3]  + A[10]*f[6] + A[28]*f[19];
  R[8]  = f[7];
  R[9]  = f[8];
  R[10] = A[7]*f[3]  + A[12]*f[6] + A[15]*f[9] + A[32]*f[22];
  R[11] = f[10];
  R[12] = f[11];
  R[13] = f[12] + A[20]*f[13];
  R[14] = A[5]*f[3]  + A[25]*f[16];
  R[15] = f[14];
  R[16] = f[15];
  R[17] = A[11]*f[6] + A[29]*f[19];
  R[18] = f[17];
  R[19] = f[18];
  R[20] = A[16]*f[9] + A[33]*f[22];
  R[21] = f[20];
  R[22] = f[21];
  R[23] = A[21]*f[13] + f[23];
}

// packed variant: both halves share scalar A coefficients (splat)
__device__ __forceinline__ void at_update_pk(const float* __restrict__ A,
                                             const v2f* __restrict__ f,
                                             v2f* __restrict__ R) {
  R[0]  = A[0]*f[0];
  R[1]  = A[1]*f[0];
  R[2]  = f[1];
  R[3]  = f[2];
  R[4]  = A[4]*f[3]  + A[24]*f[16];
  R[5]  = f[4];
  R[6]  = f[5];
  R[7]  = A[6]*f[3]  + A[10]*f[6] + A[28]*f[19];
  R[8]  = f[7];
  R[9]  = f[8];
  R[10] = A[7]*f[3]  + A[12]*f[6] + A[15]*f[9] + A[32]*f[22];
  R[11] = f[10];
  R[12] = f[11];
  R[13] = f[12] + A[20]*f[13];
  R[14] = A[5]*f[3]  + A[25]*f[16];
  R[15] = f[14];
  R[16] = f[15];
  R[17] = A[11]*f[6] + A[29]*f[19];
  R[18] = f[17];
  R[19] = f[18];
  R[20] = A[16]*f[9] + A[33]*f[22];
  R[21] = f[20];
  R[22] = f[21];
  R[23] = A[21]*f[13] + f[23];
}

__device__ __forceinline__ float tree_sum24(const float* a) {
  float s0 = a[0]+a[1],   s1 = a[2]+a[3],   s2 = a[4]+a[5],   s3 = a[6]+a[7];
  float s4 = a[8]+a[9],   s5 = a[10]+a[11], s6 = a[12]+a[13], s7 = a[14]+a[15];
  float s8 = a[16]+a[17], s9 = a[18]+a[19], s10= a[20]+a[21], s11= a[22]+a[23];
  float u0 = s0+s1, u1 = s2+s3, u2 = s4+s5, u3 = s6+s7, u4 = s8+s9, u5 = s10+s11;
  return ((u0+u1) + (u2+u3)) + (u4+u5);
}

// unpack 24 bf16 E values (12 u32 pairs) -> f32; bf16<<16 IS f32.
__device__ __forceinline__ void unpack_ev(const unsigned* __restrict__ uu,
                                          float* __restrict__ ev) {
  #pragma unroll
  for (int j = 0; j < 12; ++j) {
    ev[2*j]   = __uint_as_float(uu[j] << 16);
    ev[2*j+1] = __uint_as_float(uu[j] & 0xFFFF0000u);
  }
}

// one normalized vector step: f <- normalize((A^T f) * ev)
__device__ __forceinline__ void vec_step(const float* __restrict__ A,
                                         const float* __restrict__ ev,
                                         float* __restrict__ f) {
  float R[NST];
  at_update(A, f, R);
  float al[NST];
  #pragma unroll
  for (int s = 0; s < NST; ++s) al[s] = R[s] * ev[s];
  float z = tree_sum24(al);
  float zr = 1.0f / z;
  #pragma unroll
  for (int s = 0; s < NST; ++s) f[s] = al[s] * zr;
}

// ------------------------------------------------------------------
// Prep (merged): block 0 builds A + packed bf16 E table (80B stride);
// other blocks build ctx codes.
// ------------------------------------------------------------------
__global__ __launch_bounds__(256) void k_prep(
    const int* __restrict__ obs,
    const float* __restrict__ wt, const float* __restrict__ we,
    unsigned* __restrict__ ebt, float* __restrict__ a35out,
    unsigned char* __restrict__ ctx8)
{
  if (blockIdx.x != 0) {
    int i = ((int)blockIdx.x - 1) * 256 + (int)threadIdx.x;
    int t = i & (TLEN - 1);
    int o0 = obs[i];
    int o1 = (t >= 1) ? obs[i-1] : 4;
    int o2 = (t >= 2) ? obs[i-2] : 4;
    ctx8[i] = (unsigned char)((o2*5 + o1)*4 + o0);
    return;
  }

  __shared__ float lg[NST * 216];
  __shared__ float pred[NST][8];
  __shared__ float rmx[NST];
  __shared__ float rrs[NST];
  int tid = threadIdx.x;
  for (int i = tid; i < NST * 216; i += 256) lg[i] = -1e30f;
  __syncthreads();

  for (int e = tid; e < 1073; e += 256) {
    int s, i, j, l, k = -1;
    if (e < 84)        { int ep=e; l=ep&3; int p=ep>>2; if (p<16){i=p>>2;j=p&3;} else {i=4;j=p-16;} s=0; k=ep; }
    else if (e < 104)  { int ep=e-84;  s=1;  i=ep>>2; j=ep&3; l=0; k=84+ep; }
    else if (e < 108)  { int ep=e-104; s=2;  i=ep;    j=0;    l=3; k=104+ep; }
    else if (e < 109)  { s=3; i=0; j=3; l=2; }
    else if (e < 113)  { int ep=e-109; s=4;  i=3; j=2; l=ep;  k=108+ep; }
    else if (e < 129)  { int ep=e-113; s=5;  i=2; j=ep>>2; l=ep&3; k=112+ep; }
    else if (e < 385)  { int ep=e-129; s=6+(ep>>6); int q=ep&63; i=q>>4; j=(q>>2)&3; l=q&3; k=128+ep; }
    else if (e < 401)  { int ep=e-385; s=10; i=ep>>2; j=ep&3; l=3; k=384+ep; }
    else if (e < 405)  { int ep=e-401; s=11; i=ep; j=3; l=0; k=400+ep; }
    else if (e < 409)  { int ep=e-405; s=11; i=ep; j=3; l=2; k=404+ep; }
    else if (e < 412)  { int ep=e-409; s=12; i=3; j=(ep==2)?2:0; l=(ep==1)?2:0; }
    else if (e < 476)  { int ep=e-412; s=13; i=ep>>4; j=(ep>>2)&3; l=ep&3; k=408+ep; }
    else if (e < 1052) { int ep=e-476; s=14+(ep>>6); int q=ep&63; i=q>>4; j=(q>>2)&3; l=q&3; k=472+ep; }
    else if (e < 1068) { int ep=e-1052; s=23; i=ep>>2; j=ep&3; l=5; k=1048+ep; }
    else if (e < 1072) { int ep=e-1068; s=23; i=ep; j=5; l=5; k=1064+ep; }
    else               { s=23; i=5; j=5; l=5; }
    float v = (k < 0) ? 1.0f : we[k];
    lg[s*216 + i*36 + j*6 + l] = v;
  }
  __syncthreads();

  if (tid < 192) {
    int s = tid >> 3, k = tid & 7;
    const float* base = lg + s*216 + k*27;
    float mx = base[0];
    for (int x = 1; x < 27; ++x) mx = fmaxf(mx, base[x]);
    pred[s][k] = mx;
  }
  __syncthreads();
  if (tid < NST) {
    float mx = pred[tid][0];
    #pragma unroll
    for (int k = 1; k < 8; ++k) mx = fmaxf(mx, pred[tid][k]);
    rmx[tid] = mx;
  }
  __syncthreads();
  if (tid < 192) {
    int s = tid >> 3, k = tid & 7;
    const float* base = lg + s*216 + k*27;
    float m = rmx[s];
    float sm = 0.f;
    for (int x = 0; x < 27; ++x) sm += __expf(base[x] - m);
    pred[s][k] = sm;
  }
  __syncthreads();
  if (tid < NST) {
    float sm = 0.f;
    #pragma unroll
    for (int k = 0; k < 8; ++k) sm += pred[tid][k];
    rrs[tid] = 1.0f / sm;
  }
  __syncthreads();

  if (tid < NCTX) {
    int c2 = tid / 20, c1 = (tid >> 2) % 5, c0 = tid & 3;
    int x = c2*36 + c1*6 + c0;
    float v[NST];
    float m = 1e-30f;
    for (int s = 0; s < NST; ++s) {
      v[s] = __expf(lg[s*216 + x] - rmx[s]) * rrs[s];
      m = fmaxf(m, v[s]);
    }
    float im = 1.0f / m;
    unsigned* row = ebt + tid * EWRD;
    #pragma unroll
    for (int j = 0; j < 12; ++j)
      row[j] = (unsigned)f2bf(v[2*j]*im) | ((unsigned)f2bf(v[2*j+1]*im) << 16);
    row[12] = __float_as_uint(__logf(m));
    #pragma unroll
    for (int j = 13; j < EWRD; ++j) row[j] = 0u;
  }

  if (tid == 0) {
    float w[10];
    for (int q = 0; q < 10; ++q) w[q] = wt[q];
    float la[35];
    float d2 = 1.f - w[9]*w[9];
    float d3 = 1.f - w[9]*w[9]*w[9];
    la[0]=1.f-w[0]; la[1]=w[0];
    la[2]=1.f; la[3]=1.f;
    la[4]=w[1]; la[5]=w[3]; la[6]=d2; la[7]=d3;
    la[8]=1.f; la[9]=1.f;
    la[10]=w[2]; la[11]=w[4]; la[12]=d2;
    la[13]=1.f; la[14]=1.f;
    la[15]=1.f-w[5]; la[16]=w[5];
    la[17]=1.f; la[18]=1.f; la[19]=1.f;
    la[20]=1.f; la[21]=1.f;
    la[22]=1.f; la[23]=1.f;
    la[24]=w[6]; la[25]=1.f-w[6];
    la[26]=1.f; la[27]=1.f;
    la[28]=w[7]; la[29]=1.f-w[7];
    la[30]=1.f; la[31]=1.f;
    la[32]=w[8]; la[33]=1.f-w[8];
    la[34]=1.f;
    const int rs[25] = {0,2,3,4,8,9,10,13,14,15,17,18,19,20,22,23,24,26,27,28,30,31,32,34,35};
    for (int r = 0; r < 24; ++r) {
      float mx = -1e30f;
      for (int e = rs[r]; e < rs[r+1]; ++e) mx = fmaxf(mx, la[e]);
      float sm = 0.f;
      for (int e = rs[r]; e < rs[r+1]; ++e) sm += expf(la[e] - mx);
      float inv = 1.0f / sm;
      for (int e = rs[r]; e < rs[r+1]; ++e) a35out[e] = expf(la[e] - mx) * inv;
    }
  }
}

// ------------------------------------------------------------------
// Phase A (packed-FP32 + bf16 E @80B stride): group = 16 lanes per
// (chunk, batch); lane g<12 owns column PAIR (2g,2g+1) as float2.
// E row read = 3 x ds_read_b128 + 1 x b32 (HALF the banked LDS bytes
// of the f32/ESTR=28 table; 80B stride = 5 quads, coprime with 8 ->
// full bank-quad spread, unlike r14's 64B-stride collapse).
// ------------------------------------------------------------------
__global__ __launch_bounds__(256, 3) void k_phaseA(
    const unsigned char* __restrict__ ctx8,
    const unsigned* __restrict__ ebt,
    const float* __restrict__ a35,
    unsigned short* __restrict__ M,
    unsigned short* __restrict__ csumb,
    float* __restrict__ lsb)
{
  constexpr int L = TLEN / CBT;            // 32
  constexpr int GPA = 16;                  // batches per 256-block
  constexpr int WORDS = L / 4;             // 8
  __shared__ __align__(16) char smem[8 * NST * ESTR * 4];   // 21504 B (union)
  unsigned* et = (unsigned*)smem;          // 8000 B live during main loop
  for (int i = threadIdx.x; i < NCTX * EWRD; i += 256) et[i] = ebt[i];
  float A[35];
  #pragma unroll
  for (int e = 0; e < 35; ++e) A[e] = sload(a35 + e);
  __syncthreads();

  int c   = (int)blockIdx.x / (BATCH / GPA);   // chunk
  int bb  = (int)blockIdx.x % (BATCH / GPA);
  int grp = (int)threadIdx.x >> 4;             // 0..15
  int g   = (int)threadIdx.x & 15;
  int b   = bb * GPA + grp;
  bool act = g < 12;
  int col0 = g * 2;

  v2f m[NST];
  #pragma unroll
  for (int s = 0; s < NST; ++s) {
    m[s].x = (s == col0)     ? 1.0f : 0.0f;
    m[s].y = (s == col0 + 1) ? 1.0f : 0.0f;
  }

  const unsigned char* cb = ctx8 + (size_t)b * TLEN;
  const uint4* etb = (const uint4*)et;     // row = 5 uint4
  const float* etf = (const float*)et;
  float ls = 0.0f;                   // uniform across group
  float lscx = 0.0f, lscy = 0.0f;    // per-column log scales
  const int t0 = c * L;

  int kk0 = 0;
  if (c == 0) {          // peel word 0: t=0 folds into ll0
    unsigned w = *(const unsigned*)cb;
    int ctx0 = (int)(w & 0xFFu);
    float e00 = __uint_as_float(et[ctx0*EWRD] << 16);
    ls = __logf(e00) + etf[ctx0*EWRD + 12];
    #pragma unroll
    for (int j = 1; j < 4; ++j) {
      int ctx = (int)((w >> (8*j)) & 0xFFu);
      uint4 w0 = etb[ctx*5], w1 = etb[ctx*5+1], w2 = etb[ctx*5+2];
      ls += etf[ctx*EWRD + 12];
      unsigned uu[12] = {w0.x,w0.y,w0.z,w0.w, w1.x,w1.y,w1.z,w1.w, w2.x,w2.y,w2.z,w2.w};
      float ev[NST];
      unpack_ev(uu, ev);
      v2f R[NST];
      at_update_pk(A, m, R);
      #pragma unroll
      for (int s = 0; s < NST; ++s) m[s] = R[s] * ev[s];
    }
    kk0 = 1;
  }

  for (int kk = kk0; kk < WORDS; ++kk) {
    unsigned w = *(const unsigned*)(cb + t0 + kk*4);
    #pragma unroll
    for (int j = 0; j < 4; ++j) {
      int ctx = (int)((w >> (8*j)) & 0xFFu);
      uint4 w0 = etb[ctx*5], w1 = etb[ctx*5+1], w2 = etb[ctx*5+2];
      ls += etf[ctx*EWRD + 12];
      unsigned uu[12] = {w0.x,w0.y,w0.z,w0.w, w1.x,w1.y,w1.z,w1.w, w2.x,w2.y,w2.z,w2.w};
      float ev[NST];
      unpack_ev(uu, ev);
      v2f R[NST];
      at_update_pk(A, m, R);
      #pragma unroll
      for (int s = 0; s < NST; ++s) m[s] = R[s] * ev[s];
    }
    if (kk == 3) {                  // renorm halfway (per component)
      float cx = 0.f, cy = 0.f;
      #pragma unroll
      for (int s = 0; s < NST; ++s) { cx = fmaxf(cx, m[s].x); cy = fmaxf(cy, m[s].y); }
      float rx, ry;
      if (cx > 1e-35f) { lscx += __logf(cx); rx = 1.0f/cx; } else { lscx = -1e30f; rx = 0.f; }
      if (cy > 1e-35f) { lscy += __logf(cy); ry = 1.0f/cy; } else { lscy = -1e30f; ry = 0.f; }
      v2f rr; rr.x = rx; rr.y = ry;
      #pragma unroll
      for (int s = 0; s < NST; ++s) m[s] *= rr;
    }
  }

  // final per-column renorm
  {
    float cx = 0.f, cy = 0.f;
    #pragma unroll
    for (int s = 0; s < NST; ++s) { cx = fmaxf(cx, m[s].x); cy = fmaxf(cy, m[s].y); }
    float rx, ry;
    if (cx > 1e-35f) { lscx += __logf(cx); rx = 1.0f/cx; } else { lscx = -1e30f; rx = 0.f; }
    if (cy > 1e-35f) { lscy += __logf(cy); ry = 1.0f/cy; } else { lscy = -1e30f; ry = 0.f; }
    v2f rr; rr.x = rx; rr.y = ry;
    #pragma unroll
    for (int s = 0; s < NST; ++s) m[s] *= rr;
  }

  // csm = max over the group's 24 columns (width-16 shuffle)
  float tl = act ? fmaxf(lscx, lscy) : -1e30f;
  #pragma unroll
  for (int o = 1; o < 16; o <<= 1) tl = fmaxf(tl, __shfl_xor(tl, o, 16));
  float csm = tl;
  float facx = act ? __expf(lscx - csm) : 0.f;   // 0 for dead cols
  float facy = act ? __expf(lscy - csm) : 0.f;
  {
    v2f ff; ff.x = facx; ff.y = facy;
    #pragma unroll
    for (int s = 0; s < NST; ++s) m[s] *= ff;
  }

  if (act) {
    float sx = 0.f, sy = 0.f;
    #pragma unroll
    for (int s = 0; s < NST; ++s) { sx += m[s].x; sy += m[s].y; }
    ushort2 sv; sv.x = f2bf(sx); sv.y = f2bf(sy);
    *(ushort2*)(csumb + (size_t)(c*BATCH + b)*NST + col0) = sv;
  }

  // ---- reuse smem as transpose buffer: two passes of 8 groups ----
  __syncthreads();
  float (*tr)[NST][ESTR] = (float (*)[NST][ESTR])smem;
  #pragma unroll
  for (int pass = 0; pass < 2; ++pass) {
    int pg = grp - pass*8;
    bool in = (pg >= 0 && pg < 8);
    if (in && act) {
      #pragma unroll
      for (int s = 0; s < NST; ++s) {
        tr[pg][s][col0]   = m[s].x;
        tr[pg][s][col0+1] = m[s].y;
      }
    }
    __syncthreads();
    if (in && act) {
      #pragma unroll
      for (int rr2 = 0; rr2 < 2; ++rr2) {
        int row = col0 + rr2;
        const float4* rp = (const float4*)(&tr[pg][row][0]);
        float rowv[NST];
        #pragma unroll
        for (int j = 0; j < 6; ++j) {
          float4 q = rp[j];
          rowv[4*j] = q.x; rowv[4*j+1] = q.y; rowv[4*j+2] = q.z; rowv[4*j+3] = q.w;
        }
        unsigned pk[12];
        #pragma unroll
        for (int j = 0; j < 12; ++j)
          pk[j] = (unsigned)f2bf(rowv[2*j]) | ((unsigned)f2bf(rowv[2*j+1]) << 16);
        uint4* op = (uint4*)(M + ((size_t)(c*BATCH + b))*(NST*NST) + row*NST);
        op[0] = make_uint4(pk[0], pk[1], pk[2],  pk[3]);
        op[1] = make_uint4(pk[4], pk[5], pk[6],  pk[7]);
        op[2] = make_uint4(pk[8], pk[9], pk[10], pk[11]);
      }
    }
    __syncthreads();
  }
  if (g == 0) lsb[c*BATCH + b] = ls + csm;
}

// ------------------------------------------------------------------
// Phase B: scan over CBT chunks; 32-lane group per batch, 4-deep register
// prefetch. z from in-lane colsum dot; broadcast via LDS.
// ------------------------------------------------------------------
__global__ __launch_bounds__(64) void k_phaseB(
    const unsigned short* __restrict__ M,
    const unsigned short* __restrict__ csumb,
    const float* __restrict__ lsb,
    float* __restrict__ vbc,
    float* __restrict__ alphas,
    float* __restrict__ llout)
{
  __shared__ __align__(16) float xfer[64];
  int lane = (int)threadIdx.x;
  int sub  = lane >> 5;
  int g    = lane & 31;
  bool act = g < NST;
  int gi   = act ? g : 0;
  int b    = (int)blockIdx.x * 2 + sub;

  float p[NST];
  #pragma unroll
  for (int j = 0; j < NST; ++j) p[j] = (j == 0) ? 1.0f : 0.0f;

  if (act) {
    vbc[((size_t)b*CBT + 0)*NST + g] = (g == 0) ? 1.0f : 0.0f;
    alphas[(size_t)b*TLEN*NST + g]   = (g == 0) ? 1.0f : 0.0f;   // t = 0 row
  }

  uint4 pfM[4][3];
  uint4 pfS[4][3];
  float pfL[4];
  #pragma unroll
  for (int i = 0; i < 4; ++i) {
    const uint4* mp = (const uint4*)(M + (((size_t)(i*BATCH + b))*NST + gi)*NST);
    pfM[i][0] = mp[0]; pfM[i][1] = mp[1]; pfM[i][2] = mp[2];
    const uint4* sp = (const uint4*)(csumb + (size_t)(i*BATCH + b)*NST);
    pfS[i][0] = sp[0]; pfS[i][1] = sp[1]; pfS[i][2] = sp[2];
    pfL[i] = lsb[i*BATCH + b];
  }

  float ll = 0.0f;
  for (int cc = 0; cc < CBT; cc += 4) {
    #pragma unroll
    for (int i = 0; i < 4; ++i) {
      int c = cc + i;
      float mr[NST];
      {
        unsigned uu[12] = {pfM[i][0].x,pfM[i][0].y,pfM[i][0].z,pfM[i][0].w,
                           pfM[i][1].x,pfM[i][1].y,pfM[i][1].z,pfM[i][1].w,
                           pfM[i][2].x,pfM[i][2].y,pfM[i][2].z,pfM[i][2].w};
        #pragma unroll
        for (int j = 0; j < 12; ++j) {
          mr[2*j]   = __uint_as_float(uu[j] << 16);
          mr[2*j+1] = __uint_as_float(uu[j] & 0xFFFF0000u);
        }
      }
      float sv[NST];
      {
        unsigned uu[12] = {pfS[i][0].x,pfS[i][0].y,pfS[i][0].z,pfS[i][0].w,
                           pfS[i][1].x,pfS[i][1].y,pfS[i][1].z,pfS[i][1].w,
                           pfS[i][2].x,pfS[i][2].y,pfS[i][2].z,pfS[i][2].w};
        #pragma unroll
        for (int j = 0; j < 12; ++j) {
          sv[2*j]   = __uint_as_float(uu[j] << 16);
          sv[2*j+1] = __uint_as_float(uu[j] & 0xFFFF0000u);
        }
      }
      float lsT = pfL[i];

      int cn = c + 4;
      if (cn < CBT) {
        const uint4* mp = (const uint4*)(M + (((size_t)(cn*BATCH + b))*NST + gi)*NST);
        pfM[i][0] = mp[0]; pfM[i][1] = mp[1]; pfM[i][2] = mp[2];
        const uint4* sp = (const uint4*)(csumb + (size_t)(cn*BATCH + b)*NST);
        pfS[i][0] = sp[0]; pfS[i][1] = sp[1]; pfS[i][2] = sp[2];
        pfL[i] = lsb[cn*BATCH + b];
      }

      float pr[NST], zz[NST];
      #pragma unroll
      for (int j = 0; j < NST; ++j) { pr[j] = mr[j] * p[j]; zz[j] = sv[j] * p[j]; }
      float nv = tree_sum24(pr);
      float z  = tree_sum24(zz);
      float zr = 1.0f / z;
      float fn = nv * zr;

      ll += __logf(z) + lsT;

      if (act && c + 1 < CBT) vbc[((size_t)b*CBT + c + 1)*NST + g] = fn;

      xfer[sub*32 + g] = fn;
      __syncthreads();
      {
        const float4* x4 = (const float4*)(&xfer[sub*32]);
        float4 q0 = x4[0], q1 = x4[1], q2 = x4[2],
               q3 = x4[3], q4 = x4[4], q5 = x4[5];
        p[0]=q0.x; p[1]=q0.y; p[2]=q0.z; p[3]=q0.w;
        p[4]=q1.x; p[5]=q1.y; p[6]=q1.z; p[7]=q1.w;
        p[8]=q2.x; p[9]=q2.y; p[10]=q2.z; p[11]=q2.w;
        p[12]=q3.x; p[13]=q3.y; p[14]=q3.z; p[15]=q3.w;
        p[16]=q4.x; p[17]=q4.y; p[18]=q4.z; p[19]=q4.w;
        p[20]=q5.x; p[21]=q5.y; p[22]=q5.z; p[23]=q5.w;
      }
      __syncthreads();
    }
  }
  if (g == 0) llout[b] = ll;
}

// ------------------------------------------------------------------
// Phase C (FPC=1, zero replay, bf16 E): wave = batch b; lane g owns
// coarse chunk g. 8 slices of {4 compute steps -> stage into wave-
// private padded LDS segment -> 24-instr full-line copy-out}.
// ------------------------------------------------------------------
__global__ __launch_bounds__(128) void k_phaseC(
    const unsigned char* __restrict__ ctx8,
    const unsigned* __restrict__ ebt,
    const float* __restrict__ a35,
    const float* __restrict__ vbc,
    float* __restrict__ alphas)
{
  constexpr int CL = TLEN / CBT;     // 32 rows per chunk
  __shared__ __align__(16) unsigned et[NCTX * EWRD];         // 8000 B
  __shared__ __align__(16) float sbuf[2][64 * SEGF];         // 51200 B
  for (int i = threadIdx.x; i < NCTX * EWRD; i += 128) et[i] = ebt[i];
  float A[35];
  #pragma unroll
  for (int e = 0; e < 35; ++e) A[e] = sload(a35 + e);
  __syncthreads();

  int wv = (int)threadIdx.x >> 6;
  int b  = (int)blockIdx.x * 2 + wv;    // batch owned by this wave
  int g  = (int)threadIdx.x & 63;       // coarse chunk owned by this lane

  float f[NST];
  {
    const float4* p = (const float4*)(vbc + ((size_t)b*CBT + g) * NST);
    #pragma unroll
    for (int j = 0; j < 6; ++j) {
      float4 q = p[j];
      f[4*j] = q.x; f[4*j+1] = q.y; f[4*j+2] = q.z; f[4*j+3] = q.w;
    }
  }

  const unsigned char* cb = ctx8 + (size_t)b * TLEN;
  const uint4* etb = (const uint4*)et;  // row = 5 uint4
  float* myb = &sbuf[wv][0];
  float4* outb = (float4*)(alphas + ((size_t)b*TLEN) * NST);

  int t = g * CL;
  for (int it = 0; it < CL / SLC; ++it) {    // 8 slices of 4 rows
    unsigned wd = *(const unsigned*)(cb + t);
    #pragma unroll
    for (int j = 0; j < SLC; ++j) {
      if (t != 0) {                          // t==0 row = boundary (one-hot)
        int ctx = (int)((wd >> (8*j)) & 0xFFu);
        uint4 w0 = etb[ctx*5], w1 = etb[ctx*5+1], w2 = etb[ctx*5+2];
        unsigned uu[12] = {w0.x,w0.y,w0.z,w0.w, w1.x,w1.y,w1.z,w1.w,
                           w2.x,w2.y,w2.z,w2.w};
        float ev[NST];
        unpack_ev(uu, ev);
        vec_step(A, ev, f);
      }
      float4* d4 = (float4*)(myb + g*SEGF + j*NST);
      d4[0] = make_float4(f[0],  f[1],  f[2],  f[3]);
      d4[1] = make_float4(f[4],  f[5],  f[6],  f[7]);
      d4[2] = make_float4(f[8],  f[9],  f[10], f[11]);
      d4[3] = make_float4(f[12], f[13], f[14], f[15]);
      d4[4] = make_float4(f[16], f[17], f[18], f[19]);
      d4[5] = make_float4(f[20], f[21], f[22], f[23]);
      ++t;
    }

    // copy-out slice: rows [it*4, it*4+4) of every chunk.
    float4* out4 = outb + (size_t)it * SLC * 6;
    #pragma unroll
    for (int i = 0; i < 24; ++i) {
      int j   = i * 64 + g;
      int seg = (int)(((unsigned)j * 2731u) >> 16);   // j/24 for j<1536
      int off = j - seg * 24;
      float4 v = *(const float4*)(myb + seg*SEGF + off*4);
      out4[seg * (CL*6) + off] = v;        // chunk stride = 32 rows * 6 quads
    }
  }
}

// ------------------------------------------------------------------
extern "C" void kernel_launch(void* const* d_in, const int* in_sizes, int n_in,
                              void* d_out, int out_size, void* d_ws, size_t ws_size,
                              hipStream_t stream)
{
  (void)in_sizes; (void)n_in; (void)out_size; (void)ws_size;
  const int*   obs = (const int*)d_in[0];
  const float* wt  = (const float*)d_in[1];
  const float* we  = (const float*)d_in[2];
  // d_in[3] (init_kernel) is mathematically unused: softmax of 1 element == 1.

  float* out    = (float*)d_out;
  float* alphas = out;
  float* llout  = out + (size_t)BATCH * TLEN * NST;

  char* ws = (char*)d_ws;
  const size_t EBT_OFF  = 0;                                         // 8000 B
  const size_t A_OFF    = 12 * 1024;
  const size_t CTX_OFF  = 16 * 1024;                                 // 1 MiB
  const size_t LS_OFF   = CTX_OFF + (size_t)BATCH * TLEN;            // CBT*512*4
  const size_t CS_OFF   = LS_OFF + (size_t)CBT * BATCH * 4;          // CBT*512*24*2
  const size_t VBC_OFF  = CS_OFF + (size_t)CBT * BATCH * NST * 2;    // 512*CBT*24*4
  const size_t M_OFF    = VBC_OFF + (size_t)BATCH * CBT * NST * 4;   // CBT*512*576*2

  unsigned* ebt = (unsigned*)(ws + EBT_OFF);
  float* a35  = (float*)(ws + A_OFF);
  unsigned char* ctx8 = (unsigned char*)(ws + CTX_OFF);
  float* lsb  = (float*)(ws + LS_OFF);
  unsigned short* csumb = (unsigned short*)(ws + CS_OFF);
  float* vbc  = (float*)(ws + VBC_OFF);
  unsigned short* mbuf = (unsigned short*)(ws + M_OFF);

  k_prep<<<1 + (BATCH * TLEN) / 256, 256, 0, stream>>>(obs, wt, we, ebt, a35, ctx8);
  k_phaseA<<<CBT * (BATCH / 16), 256, 0, stream>>>(ctx8, ebt, a35, mbuf, csumb, lsb);
  k_phaseB<<<BATCH / 2, 64, 0, stream>>>(mbuf, csumb, lsb, vbc, alphas, llout);
  k_phaseC<<<BATCH / 2, 128, 0, stream>>>(ctx8, ebt, a35, vbc, alphas);
}

// Round 23
// 123.627 us; speedup vs baseline: 1.0662x; 1.0662x over previous
//
#include <hip/hip_runtime.h>

#define BATCH 512
#define TLEN  2048
#define NST   24
#define ESTR  28          // floats per ctx row in E table: 24 E + lognorm + 3 pad
#define NCTX  100         // ctx = (c2*5 + c1)*4 + c0  (c2,c1 in 0..4, c0 in 0..3)
#define CBT   64          // coarse chunks (phase A matrices, phase B scan length)
#define SLC   4           // rows staged per slice
#define SEGF  100         // padded floats per staged segment (96 data + 4 pad)

typedef float v2f __attribute__((ext_vector_type(2)));

__device__ __forceinline__ unsigned short f2bf(float x) {
  unsigned u = __float_as_uint(x);
  u += 0x7FFFu + ((u >> 16) & 1u);
  return (unsigned short)(u >> 16);
}

__device__ __forceinline__ float sload(const float* p) {
  return __uint_as_float(__builtin_amdgcn_readfirstlane(__float_as_uint(*p)));
}

// R[dst] = sum over edges (src->dst) of A[edge]*f[src].
// STRUCTURE-OPT: single-edge rows have softmax == exactly 1.0 -> identity edges.
__device__ __forceinline__ void at_update(const float* __restrict__ A,
                                          const float* __restrict__ f,
                                          float* __restrict__ R) {
  R[0]  = A[0]*f[0];
  R[1]  = A[1]*f[0];
  R[2]  = f[1];
  R[3]  = f[2];
  R[4]  = A[4]*f[3]  + A[24]*f[16];
  R[5]  = f[4];
  R[6]  = f[5];
  R[7]  = A[6]*f[3]  + A[10]*f[6] + A[28]*f[19];
  R[8]  = f[7];
  R[9]  = f[8];
  R[10] = A[7]*f[3]  + A[12]*f[6] + A[15]*f[9] + A[32]*f[22];
  R[11] = f[10];
  R[12] = f[11];
  R[13] = f[12] + A[20]*f[13];
  R[14] = A[5]*f[3]  + A[25]*f[16];
  R[15] = f[14];
  R[16] = f[15];
  R[17] = A[11]*f[6] + A[29]*f[19];
  R[18] = f[17];
  R[19] = f[18];
  R[20] = A[16]*f[9] + A[33]*f[22];
  R[21] = f[20];
  R[22] = f[21];
  R[23] = A[21]*f[13] + f[23];
}

// packed variant: both halves share scalar A coefficients (splat)
__device__ __forceinline__ void at_update_pk(const float* __restrict__ A,
                                             const v2f* __restrict__ f,
                                             v2f* __restrict__ R) {
  R[0]  = A[0]*f[0];
  R[1]  = A[1]*f[0];
  R[2]  = f[1];
  R[3]  = f[2];
  R[4]  = A[4]*f[3]  + A[24]*f[16];
  R[5]  = f[4];
  R[6]  = f[5];
  R[7]  = A[6]*f[3]  + A[10]*f[6] + A[28]*f[19];
  R[8]  = f[7];
  R[9]  = f[8];
  R[10] = A[7]*f[3]  + A[12]*f[6] + A[15]*f[9] + A[32]*f[22];
  R[11] = f[10];
  R[12] = f[11];
  R[13] = f[12] + A[20]*f[13];
  R[14] = A[5]*f[3]  + A[25]*f[16];
  R[15] = f[14];
  R[16] = f[15];
  R[17] = A[11]*f[6] + A[29]*f[19];
  R[18] = f[17];
  R[19] = f[18];
  R[20] = A[16]*f[9] + A[33]*f[22];
  R[21] = f[20];
  R[22] = f[21];
  R[23] = A[21]*f[13] + f[23];
}

__device__ __forceinline__ float tree_sum24(const float* a) {
  float s0 = a[0]+a[1],   s1 = a[2]+a[3],   s2 = a[4]+a[5],   s3 = a[6]+a[7];
  float s4 = a[8]+a[9],   s5 = a[10]+a[11], s6 = a[12]+a[13], s7 = a[14]+a[15];
  float s8 = a[16]+a[17], s9 = a[18]+a[19], s10= a[20]+a[21], s11= a[22]+a[23];
  float u0 = s0+s1, u1 = s2+s3, u2 = s4+s5, u3 = s6+s7, u4 = s8+s9, u5 = s10+s11;
  return ((u0+u1) + (u2+u3)) + (u4+u5);
}

// one normalized vector step: f <- normalize((A^T f) * ev)
__device__ __forceinline__ void vec_step(const float* __restrict__ A,
                                         const float* __restrict__ ev,
                                         float* __restrict__ f) {
  float R[NST];
  at_update(A, f, R);
  float al[NST];
  #pragma unroll
  for (int s = 0; s < NST; ++s) al[s] = R[s] * ev[s];
  float z = tree_sum24(al);
  float zr = 1.0f / z;
  #pragma unroll
  for (int s = 0; s < NST; ++s) f[s] = al[s] * zr;
}

__device__ __forceinline__ void load_ev(const float4* __restrict__ etb, int ctx,
                                        float* __restrict__ ev) {
  const float4* ep = etb + ctx * 7;
  #pragma unroll
  for (int j = 0; j < 6; ++j) {
    float4 q = ep[j];
    ev[4*j] = q.x; ev[4*j+1] = q.y; ev[4*j+2] = q.z; ev[4*j+3] = q.w;
  }
}

// ------------------------------------------------------------------
// Prep (merged): block 0 builds A + E tables; other blocks build ctx codes.
// ------------------------------------------------------------------
__global__ __launch_bounds__(256) void k_prep(
    const int* __restrict__ obs,
    const float* __restrict__ wt, const float* __restrict__ we,
    float* __restrict__ etab, float* __restrict__ a35out,
    unsigned char* __restrict__ ctx8)
{
  if (blockIdx.x != 0) {
    int i = ((int)blockIdx.x - 1) * 256 + (int)threadIdx.x;
    int t = i & (TLEN - 1);
    int o0 = obs[i];
    int o1 = (t >= 1) ? obs[i-1] : 4;
    int o2 = (t >= 2) ? obs[i-2] : 4;
    ctx8[i] = (unsigned char)((o2*5 + o1)*4 + o0);
    return;
  }

  __shared__ float lg[NST * 216];
  __shared__ float pred[NST][8];
  __shared__ float rmx[NST];
  __shared__ float rrs[NST];
  int tid = threadIdx.x;
  for (int i = tid; i < NST * 216; i += 256) lg[i] = -1e30f;
  __syncthreads();

  for (int e = tid; e < 1073; e += 256) {
    int s, i, j, l, k = -1;
    if (e < 84)        { int ep=e; l=ep&3; int p=ep>>2; if (p<16){i=p>>2;j=p&3;} else {i=4;j=p-16;} s=0; k=ep; }
    else if (e < 104)  { int ep=e-84;  s=1;  i=ep>>2; j=ep&3; l=0; k=84+ep; }
    else if (e < 108)  { int ep=e-104; s=2;  i=ep;    j=0;    l=3; k=104+ep; }
    else if (e < 109)  { s=3; i=0; j=3; l=2; }
    else if (e < 113)  { int ep=e-109; s=4;  i=3; j=2; l=ep;  k=108+ep; }
    else if (e < 129)  { int ep=e-113; s=5;  i=2; j=ep>>2; l=ep&3; k=112+ep; }
    else if (e < 385)  { int ep=e-129; s=6+(ep>>6); int q=ep&63; i=q>>4; j=(q>>2)&3; l=q&3; k=128+ep; }
    else if (e < 401)  { int ep=e-385; s=10; i=ep>>2; j=ep&3; l=3; k=384+ep; }
    else if (e < 405)  { int ep=e-401; s=11; i=ep; j=3; l=0; k=400+ep; }
    else if (e < 409)  { int ep=e-405; s=11; i=ep; j=3; l=2; k=404+ep; }
    else if (e < 412)  { int ep=e-409; s=12; i=3; j=(ep==2)?2:0; l=(ep==1)?2:0; }
    else if (e < 476)  { int ep=e-412; s=13; i=ep>>4; j=(ep>>2)&3; l=ep&3; k=408+ep; }
    else if (e < 1052) { int ep=e-476; s=14+(ep>>6); int q=ep&63; i=q>>4; j=(q>>2)&3; l=q&3; k=472+ep; }
    else if (e < 1068) { int ep=e-1052; s=23; i=ep>>2; j=ep&3; l=5; k=1048+ep; }
    else if (e < 1072) { int ep=e-1068; s=23; i=ep; j=5; l=5; k=1064+ep; }
    else               { s=23; i=5; j=5; l=5; }
    float v = (k < 0) ? 1.0f : we[k];
    lg[s*216 + i*36 + j*6 + l] = v;
  }
  __syncthreads();

  if (tid < 192) {
    int s = tid >> 3, k = tid & 7;
    const float* base = lg + s*216 + k*27;
    float mx = base[0];
    for (int x = 1; x < 27; ++x) mx = fmaxf(mx, base[x]);
    pred[s][k] = mx;
  }
  __syncthreads();
  if (tid < NST) {
    float mx = pred[tid][0];
    #pragma unroll
    for (int k = 1; k < 8; ++k) mx = fmaxf(mx, pred[tid][k]);
    rmx[tid] = mx;
  }
  __syncthreads();
  if (tid < 192) {
    int s = tid >> 3, k = tid & 7;
    const float* base = lg + s*216 + k*27;
    float m = rmx[s];
    float sm = 0.f;
    for (int x = 0; x < 27; ++x) sm += __expf(base[x] - m);
    pred[s][k] = sm;
  }
  __syncthreads();
  if (tid < NST) {
    float sm = 0.f;
    #pragma unroll
    for (int k = 0; k < 8; ++k) sm += pred[tid][k];
    rrs[tid] = 1.0f / sm;
  }
  __syncthreads();

  if (tid < NCTX) {
    int c2 = tid / 20, c1 = (tid >> 2) % 5, c0 = tid & 3;
    int x = c2*36 + c1*6 + c0;
    float v[NST];
    float m = 1e-30f;
    for (int s = 0; s < NST; ++s) {
      v[s] = __expf(lg[s*216 + x] - rmx[s]) * rrs[s];
      m = fmaxf(m, v[s]);
    }
    float im = 1.0f / m;
    for (int s = 0; s < NST; ++s) etab[tid*ESTR + s] = v[s] * im;
    etab[tid*ESTR + 24] = __logf(m);
    etab[tid*ESTR + 25] = 0.f; etab[tid*ESTR + 26] = 0.f; etab[tid*ESTR + 27] = 0.f;
  }

  if (tid == 0) {
    float w[10];
    for (int q = 0; q < 10; ++q) w[q] = wt[q];
    float la[35];
    float d2 = 1.f - w[9]*w[9];
    float d3 = 1.f - w[9]*w[9]*w[9];
    la[0]=1.f-w[0]; la[1]=w[0];
    la[2]=1.f; la[3]=1.f;
    la[4]=w[1]; la[5]=w[3]; la[6]=d2; la[7]=d3;
    la[8]=1.f; la[9]=1.f;
    la[10]=w[2]; la[11]=w[4]; la[12]=d2;
    la[13]=1.f; la[14]=1.f;
    la[15]=1.f-w[5]; la[16]=w[5];
    la[17]=1.f; la[18]=1.f; la[19]=1.f;
    la[20]=1.f; la[21]=1.f;
    la[22]=1.f; la[23]=1.f;
    la[24]=w[6]; la[25]=1.f-w[6];
    la[26]=1.f; la[27]=1.f;
    la[28]=w[7]; la[29]=1.f-w[7];
    la[30]=1.f; la[31]=1.f;
    la[32]=w[8]; la[33]=1.f-w[8];
    la[34]=1.f;
    const int rs[25] = {0,2,3,4,8,9,10,13,14,15,17,18,19,20,22,23,24,26,27,28,30,31,32,34,35};
    for (int r = 0; r < 24; ++r) {
      float mx = -1e30f;
      for (int e = rs[r]; e < rs[r+1]; ++e) mx = fmaxf(mx, la[e]);
      float sm = 0.f;
      for (int e = rs[r]; e < rs[r+1]; ++e) sm += expf(la[e] - mx);
      float inv = 1.0f / sm;
      for (int e = rs[r]; e < rs[r+1]; ++e) a35out[e] = expf(la[e] - mx) * inv;
    }
  }
}

// ------------------------------------------------------------------
// Phase A (packed-FP32): group = 16 lanes per (chunk, batch); lane g<12
// owns column PAIR (2g, 2g+1) held as float2 ext-vector. f32 E table,
// ESTR=28 (7 float4s, coprime with the 8 bank-quads). VALU/latency
// bound (bf16-E tried twice: both regressed — LDS bytes are not the
// binding resource after v2f packing).
// ------------------------------------------------------------------
__global__ __launch_bounds__(256, 3) void k_phaseA(
    const unsigned char* __restrict__ ctx8,
    const float* __restrict__ etab,
    const float* __restrict__ a35,
    unsigned short* __restrict__ M,
    unsigned short* __restrict__ csumb,
    float* __restrict__ lsb)
{
  constexpr int L = TLEN / CBT;            // 32
  constexpr int GPA = 16;                  // batches per 256-block
  constexpr int WORDS = L / 4;             // 8
  __shared__ __align__(16) char smem[8 * NST * ESTR * 4];   // 21504 B (union)
  float* et = (float*)smem;                // 11200 B live during main loop
  for (int i = threadIdx.x; i < NCTX * ESTR; i += 256) et[i] = etab[i];
  float A[35];
  #pragma unroll
  for (int e = 0; e < 35; ++e) A[e] = sload(a35 + e);
  __syncthreads();

  int c   = (int)blockIdx.x / (BATCH / GPA);   // chunk
  int bb  = (int)blockIdx.x % (BATCH / GPA);
  int grp = (int)threadIdx.x >> 4;             // 0..15
  int g   = (int)threadIdx.x & 15;
  int b   = bb * GPA + grp;
  bool act = g < 12;
  int col0 = g * 2;

  v2f m[NST];
  #pragma unroll
  for (int s = 0; s < NST; ++s) {
    m[s].x = (s == col0)     ? 1.0f : 0.0f;
    m[s].y = (s == col0 + 1) ? 1.0f : 0.0f;
  }

  const unsigned char* cb = ctx8 + (size_t)b * TLEN;
  const float4* etb = (const float4*)et;
  float ls = 0.0f;                   // uniform across group
  float lscx = 0.0f, lscy = 0.0f;    // per-column log scales
  const int t0 = c * L;

  int kk0 = 0;
  if (c == 0) {          // peel word 0: t=0 folds into ll0
    unsigned w = *(const unsigned*)cb;
    int ctx0 = (int)(w & 0xFFu);
    ls = __logf(et[ctx0*ESTR]) + et[ctx0*ESTR + 24];
    #pragma unroll
    for (int j = 1; j < 4; ++j) {
      int ctx = (int)((w >> (8*j)) & 0xFFu);
      float ev[NST];
      load_ev(etb, ctx, ev);
      ls += et[ctx*ESTR + 24];
      v2f R[NST];
      at_update_pk(A, m, R);
      #pragma unroll
      for (int s = 0; s < NST; ++s) m[s] = R[s] * ev[s];
    }
    kk0 = 1;
  }

  for (int kk = kk0; kk < WORDS; ++kk) {
    unsigned w = *(const unsigned*)(cb + t0 + kk*4);
    #pragma unroll
    for (int j = 0; j < 4; ++j) {
      int ctx = (int)((w >> (8*j)) & 0xFFu);
      float ev[NST];
      load_ev(etb, ctx, ev);
      ls += et[ctx*ESTR + 24];
      v2f R[NST];
      at_update_pk(A, m, R);
      #pragma unroll
      for (int s = 0; s < NST; ++s) m[s] = R[s] * ev[s];
    }
    if (kk == 3) {                  // renorm halfway (per component)
      float cx = 0.f, cy = 0.f;
      #pragma unroll
      for (int s = 0; s < NST; ++s) { cx = fmaxf(cx, m[s].x); cy = fmaxf(cy, m[s].y); }
      float rx, ry;
      if (cx > 1e-35f) { lscx += __logf(cx); rx = 1.0f/cx; } else { lscx = -1e30f; rx = 0.f; }
      if (cy > 1e-35f) { lscy += __logf(cy); ry = 1.0f/cy; } else { lscy = -1e30f; ry = 0.f; }
      v2f rr; rr.x = rx; rr.y = ry;
      #pragma unroll
      for (int s = 0; s < NST; ++s) m[s] *= rr;
    }
  }

  // final per-column renorm
  {
    float cx = 0.f, cy = 0.f;
    #pragma unroll
    for (int s = 0; s < NST; ++s) { cx = fmaxf(cx, m[s].x); cy = fmaxf(cy, m[s].y); }
    float rx, ry;
    if (cx > 1e-35f) { lscx += __logf(cx); rx = 1.0f/cx; } else { lscx = -1e30f; rx = 0.f; }
    if (cy > 1e-35f) { lscy += __logf(cy); ry = 1.0f/cy; } else { lscy = -1e30f; ry = 0.f; }
    v2f rr; rr.x = rx; rr.y = ry;
    #pragma unroll
    for (int s = 0; s < NST; ++s) m[s] *= rr;
  }

  // csm = max over the group's 24 columns (width-16 shuffle)
  float tl = act ? fmaxf(lscx, lscy) : -1e30f;
  #pragma unroll
  for (int o = 1; o < 16; o <<= 1) tl = fmaxf(tl, __shfl_xor(tl, o, 16));
  float csm = tl;
  float facx = act ? __expf(lscx - csm) : 0.f;   // 0 for dead cols
  float facy = act ? __expf(lscy - csm) : 0.f;
  {
    v2f ff; ff.x = facx; ff.y = facy;
    #pragma unroll
    for (int s = 0; s < NST; ++s) m[s] *= ff;
  }

  if (act) {
    float sx = 0.f, sy = 0.f;
    #pragma unroll
    for (int s = 0; s < NST; ++s) { sx += m[s].x; sy += m[s].y; }
    ushort2 sv; sv.x = f2bf(sx); sv.y = f2bf(sy);
    *(ushort2*)(csumb + (size_t)(c*BATCH + b)*NST + col0) = sv;
  }

  // ---- reuse smem as transpose buffer: two passes of 8 groups ----
  __syncthreads();
  float (*tr)[NST][ESTR] = (float (*)[NST][ESTR])smem;
  #pragma unroll
  for (int pass = 0; pass < 2; ++pass) {
    int pg = grp - pass*8;
    bool in = (pg >= 0 && pg < 8);
    if (in && act) {
      #pragma unroll
      for (int s = 0; s < NST; ++s) {
        tr[pg][s][col0]   = m[s].x;
        tr[pg][s][col0+1] = m[s].y;
      }
    }
    __syncthreads();
    if (in && act) {
      #pragma unroll
      for (int rr2 = 0; rr2 < 2; ++rr2) {
        int row = col0 + rr2;
        const float4* rp = (const float4*)(&tr[pg][row][0]);
        float rowv[NST];
        #pragma unroll
        for (int j = 0; j < 6; ++j) {
          float4 q = rp[j];
          rowv[4*j] = q.x; rowv[4*j+1] = q.y; rowv[4*j+2] = q.z; rowv[4*j+3] = q.w;
        }
        unsigned pk[12];
        #pragma unroll
        for (int j = 0; j < 12; ++j)
          pk[j] = (unsigned)f2bf(rowv[2*j]) | ((unsigned)f2bf(rowv[2*j+1]) << 16);
        uint4* op = (uint4*)(M + ((size_t)(c*BATCH + b))*(NST*NST) + row*NST);
        op[0] = make_uint4(pk[0], pk[1], pk[2],  pk[3]);
        op[1] = make_uint4(pk[4], pk[5], pk[6],  pk[7]);
        op[2] = make_uint4(pk[8], pk[9], pk[10], pk[11]);
      }
    }
    __syncthreads();
  }
  if (g == 0) lsb[c*BATCH + b] = ls + csm;
}

// ------------------------------------------------------------------
// Phase B: scan over CBT chunks; 32-lane group per batch, 4-deep register
// prefetch. z from in-lane colsum dot; broadcast via LDS.
// ------------------------------------------------------------------
__global__ __launch_bounds__(64) void k_phaseB(
    const unsigned short* __restrict__ M,
    const unsigned short* __restrict__ csumb,
    const float* __restrict__ lsb,
    float* __restrict__ vbc,
    float* __restrict__ alphas,
    float* __restrict__ llout)
{
  __shared__ __align__(16) float xfer[64];
  int lane = (int)threadIdx.x;
  int sub  = lane >> 5;
  int g    = lane & 31;
  bool act = g < NST;
  int gi   = act ? g : 0;
  int b    = (int)blockIdx.x * 2 + sub;

  float p[NST];
  #pragma unroll
  for (int j = 0; j < NST; ++j) p[j] = (j == 0) ? 1.0f : 0.0f;

  if (act) {
    vbc[((size_t)b*CBT + 0)*NST + g] = (g == 0) ? 1.0f : 0.0f;
    alphas[(size_t)b*TLEN*NST + g]   = (g == 0) ? 1.0f : 0.0f;   // t = 0 row
  }

  uint4 pfM[4][3];
  uint4 pfS[4][3];
  float pfL[4];
  #pragma unroll
  for (int i = 0; i < 4; ++i) {
    const uint4* mp = (const uint4*)(M + (((size_t)(i*BATCH + b))*NST + gi)*NST);
    pfM[i][0] = mp[0]; pfM[i][1] = mp[1]; pfM[i][2] = mp[2];
    const uint4* sp = (const uint4*)(csumb + (size_t)(i*BATCH + b)*NST);
    pfS[i][0] = sp[0]; pfS[i][1] = sp[1]; pfS[i][2] = sp[2];
    pfL[i] = lsb[i*BATCH + b];
  }

  float ll = 0.0f;
  for (int cc = 0; cc < CBT; cc += 4) {
    #pragma unroll
    for (int i = 0; i < 4; ++i) {
      int c = cc + i;
      float mr[NST];
      {
        unsigned uu[12] = {pfM[i][0].x,pfM[i][0].y,pfM[i][0].z,pfM[i][0].w,
                           pfM[i][1].x,pfM[i][1].y,pfM[i][1].z,pfM[i][1].w,
                           pfM[i][2].x,pfM[i][2].y,pfM[i][2].z,pfM[i][2].w};
        #pragma unroll
        for (int j = 0; j < 12; ++j) {
          mr[2*j]   = __uint_as_float(uu[j] << 16);
          mr[2*j+1] = __uint_as_float(uu[j] & 0xFFFF0000u);
        }
      }
      float sv[NST];
      {
        unsigned uu[12] = {pfS[i][0].x,pfS[i][0].y,pfS[i][0].z,pfS[i][0].w,
                           pfS[i][1].x,pfS[i][1].y,pfS[i][1].z,pfS[i][1].w,
                           pfS[i][2].x,pfS[i][2].y,pfS[i][2].z,pfS[i][2].w};
        #pragma unroll
        for (int j = 0; j < 12; ++j) {
          sv[2*j]   = __uint_as_float(uu[j] << 16);
          sv[2*j+1] = __uint_as_float(uu[j] & 0xFFFF0000u);
        }
      }
      float lsT = pfL[i];

      int cn = c + 4;
      if (cn < CBT) {
        const uint4* mp = (const uint4*)(M + (((size_t)(cn*BATCH + b))*NST + gi)*NST);
        pfM[i][0] = mp[0]; pfM[i][1] = mp[1]; pfM[i][2] = mp[2];
        const uint4* sp = (const uint4*)(csumb + (size_t)(cn*BATCH + b)*NST);
        pfS[i][0] = sp[0]; pfS[i][1] = sp[1]; pfS[i][2] = sp[2];
        pfL[i] = lsb[cn*BATCH + b];
      }

      float pr[NST], zz[NST];
      #pragma unroll
      for (int j = 0; j < NST; ++j) { pr[j] = mr[j] * p[j]; zz[j] = sv[j] * p[j]; }
      float nv = tree_sum24(pr);
      float z  = tree_sum24(zz);
      float zr = 1.0f / z;
      float fn = nv * zr;

      ll += __logf(z) + lsT;

      if (act && c + 1 < CBT) vbc[((size_t)b*CBT + c + 1)*NST + g] = fn;

      xfer[sub*32 + g] = fn;
      __syncthreads();
      {
        const float4* x4 = (const float4*)(&xfer[sub*32]);
        float4 q0 = x4[0], q1 = x4[1], q2 = x4[2],
               q3 = x4[3], q4 = x4[4], q5 = x4[5];
        p[0]=q0.x; p[1]=q0.y; p[2]=q0.z; p[3]=q0.w;
        p[4]=q1.x; p[5]=q1.y; p[6]=q1.z; p[7]=q1.w;
        p[8]=q2.x; p[9]=q2.y; p[10]=q2.z; p[11]=q2.w;
        p[12]=q3.x; p[13]=q3.y; p[14]=q3.z; p[15]=q3.w;
        p[16]=q4.x; p[17]=q4.y; p[18]=q4.z; p[19]=q4.w;
        p[20]=q5.x; p[21]=q5.y; p[22]=q5.z; p[23]=q5.w;
      }
      __syncthreads();
    }
  }
  if (g == 0) llout[b] = ll;
}

// ------------------------------------------------------------------
// Phase C (FPC=1, zero replay): wave = batch b; lane g owns coarse chunk
// g entirely. 8 slices of {4 compute steps -> stage 4 rows into the
// wave-private padded LDS segment -> 24-instr full-line copy-out}.
// Wave-synchronous (no barriers).
// ------------------------------------------------------------------
__global__ __launch_bounds__(128) void k_phaseC(
    const unsigned char* __restrict__ ctx8,
    const float* __restrict__ etab,
    const float* __restrict__ a35,
    const float* __restrict__ vbc,
    float* __restrict__ alphas)
{
  constexpr int CL = TLEN / CBT;     // 32 rows per chunk
  __shared__ __align__(16) float et[NCTX * ESTR];            // 11200 B
  __shared__ __align__(16) float sbuf[2][64 * SEGF];         // 51200 B
  for (int i = threadIdx.x; i < NCTX * ESTR; i += 128) et[i] = etab[i];
  float A[35];
  #pragma unroll
  for (int e = 0; e < 35; ++e) A[e] = sload(a35 + e);
  __syncthreads();

  int wv = (int)threadIdx.x >> 6;
  int b  = (int)blockIdx.x * 2 + wv;    // batch owned by this wave
  int g  = (int)threadIdx.x & 63;       // coarse chunk owned by this lane

  float f[NST];
  {
    const float4* p = (const float4*)(vbc + ((size_t)b*CBT + g) * NST);
    #pragma unroll
    for (int j = 0; j < 6; ++j) {
      float4 q = p[j];
      f[4*j] = q.x; f[4*j+1] = q.y; f[4*j+2] = q.z; f[4*j+3] = q.w;
    }
  }

  const unsigned char* cb = ctx8 + (size_t)b * TLEN;
  const float4* etb = (const float4*)et;
  float* myb = &sbuf[wv][0];
  float4* outb = (float4*)(alphas + ((size_t)b*TLEN) * NST);

  int t = g * CL;
  for (int it = 0; it < CL / SLC; ++it) {    // 8 slices of 4 rows
    unsigned wd = *(const unsigned*)(cb + t);
    #pragma unroll
    for (int j = 0; j < SLC; ++j) {
      if (t != 0) {                          // t==0 row = boundary (one-hot)
        int ctx = (int)((wd >> (8*j)) & 0xFFu);
        float ev[NST];
        load_ev(etb, ctx, ev);
        vec_step(A, ev, f);
      }
      float4* d4 = (float4*)(myb + g*SEGF + j*NST);
      d4[0] = make_float4(f[0],  f[1],  f[2],  f[3]);
      d4[1] = make_float4(f[4],  f[5],  f[6],  f[7]);
      d4[2] = make_float4(f[8],  f[9],  f[10], f[11]);
      d4[3] = make_float4(f[12], f[13], f[14], f[15]);
      d4[4] = make_float4(f[16], f[17], f[18], f[19]);
      d4[5] = make_float4(f[20], f[21], f[22], f[23]);
      ++t;
    }

    // copy-out slice: rows [it*4, it*4+4) of every chunk.
    // 24 wave-stores, each covering 8 complete 128B lines.
    float4* out4 = outb + (size_t)it * SLC * 6;
    #pragma unroll
    for (int i = 0; i < 24; ++i) {
      int j   = i * 64 + g;
      int seg = (int)(((unsigned)j * 2731u) >> 16);   // j/24 for j<1536
      int off = j - seg * 24;
      float4 v = *(const float4*)(myb + seg*SEGF + off*4);
      out4[seg * (CL*6) + off] = v;        // chunk stride = 32 rows * 6 quads
    }
  }
}

// ------------------------------------------------------------------
extern "C" void kernel_launch(void* const* d_in, const int* in_sizes, int n_in,
                              void* d_out, int out_size, void* d_ws, size_t ws_size,
                              hipStream_t stream)
{
  (void)in_sizes; (void)n_in; (void)out_size; (void)ws_size;
  const int*   obs = (const int*)d_in[0];
  const float* wt  = (const float*)d_in[1];
  const float* we  = (const float*)d_in[2];
  // d_in[3] (init_kernel) is mathematically unused: softmax of 1 element == 1.

  float* out    = (float*)d_out;
  float* alphas = out;
  float* llout  = out + (size_t)BATCH * TLEN * NST;

  char* ws = (char*)d_ws;
  const size_t ETAB_OFF = 0;                                         // 11200 B
  const size_t A_OFF    = 12 * 1024;
  const size_t CTX_OFF  = 16 * 1024;                                 // 1 MiB
  const size_t LS_OFF   = CTX_OFF + (size_t)BATCH * TLEN;            // CBT*512*4
  const size_t CS_OFF   = LS_OFF + (size_t)CBT * BATCH * 4;          // CBT*512*24*2
  const size_t VBC_OFF  = CS_OFF + (size_t)CBT * BATCH * NST * 2;    // 512*CBT*24*4
  const size_t M_OFF    = VBC_OFF + (size_t)BATCH * CBT * NST * 4;   // CBT*512*576*2

  float* etab = (float*)(ws + ETAB_OFF);
  float* a35  = (float*)(ws + A_OFF);
  unsigned char* ctx8 = (unsigned char*)(ws + CTX_OFF);
  float* lsb  = (float*)(ws + LS_OFF);
  unsigned short* csumb = (unsigned short*)(ws + CS_OFF);
  float* vbc  = (float*)(ws + VBC_OFF);
  unsigned short* mbuf = (unsigned short*)(ws + M_OFF);

  k_prep<<<1 + (BATCH * TLEN) / 256, 256, 0, stream>>>(obs, wt, we, etab, a35, ctx8);
  k_phaseA<<<CBT * (BATCH / 16), 256, 0, stream>>>(ctx8, etab, a35, mbuf, csumb, lsb);
  k_phaseB<<<BATCH / 2, 64, 0, stream>>>(mbuf, csumb, lsb, vbc, alphas, llout);
  k_phaseC<<<BATCH / 2, 128, 0, stream>>>(ctx8, etab, a35, vbc, alphas);
}